// Round 15
// baseline (168.633 us; speedup 1.0000x reference)
//
#include <hip/hip_runtime.h>

#define NN 50000
#define NE 800000
#define NF 128
#define QS (NN * 32)      // quarter stride (shorts): [q][node][32]

#define SHIFT 8
#define NB 196            // ceil(50000/256)
#define PBLOCKS 128
#define PCHUNK ((NE + PBLOCKS - 1) / PBLOCKS)   // 6250

#define NTILES ((NN + 63) / 64)   // 782
#define FBLOCKS NTILES            // one tile per block

// prep kernel block ranges
#define CVX_BLOCKS 3125   // convert_x: 50000*16 chunks / 256
#define CVW_BLOCKS 320    // convert_w: 5*16384/256
#define PREP_BLOCKS (CVX_BLOCKS + CVW_BLOCKS + PBLOCKS)

typedef __attribute__((ext_vector_type(4))) float f32x4;
typedef __attribute__((ext_vector_type(2))) float f32x2;
typedef __attribute__((ext_vector_type(8))) short bf16x8;

__device__ __forceinline__ short f2bf(float f) {
    unsigned u = __float_as_uint(f);
    u += 0x7FFF + ((u >> 16) & 1);      // round-to-nearest-even
    return (short)(u >> 16);
}
__device__ __forceinline__ float bf2f(short s) {
    return __uint_as_float(((unsigned)(unsigned short)s) << 16);
}

// accumulate 8 packed bf16 (int4) into 4 float2 pairs: 1 VALU extract per
// feature (shl / and) + packed-capable f32 adds
__device__ __forceinline__ void acc8(int4 v, f32x2* a) {
    unsigned u;
    u = (unsigned)v.x;
    a[0] += (f32x2){__uint_as_float(u << 16), __uint_as_float(u & 0xffff0000u)};
    u = (unsigned)v.y;
    a[1] += (f32x2){__uint_as_float(u << 16), __uint_as_float(u & 0xffff0000u)};
    u = (unsigned)v.z;
    a[2] += (f32x2){__uint_as_float(u << 16), __uint_as_float(u & 0xffff0000u)};
    u = (unsigned)v.w;
    a[3] += (f32x2){__uint_as_float(u << 16), __uint_as_float(u & 0xffff0000u)};
}

// ---------------------------------------------------------------------------
// PREP: fused convert_x (quarter-split) + convert_w + p0 bucket counting
// ---------------------------------------------------------------------------
__global__ __launch_bounds__(256) void prep_kernel(
    const float* __restrict__ x, const float* __restrict__ g1,
    const float* __restrict__ g2, const float* __restrict__ b1,
    const float* __restrict__ b2, const float* __restrict__ lin,
    const int* __restrict__ ei, short* __restrict__ xq,
    short* __restrict__ wbf, int* __restrict__ gcnt) {
    __shared__ int cnt[2 * NB];
    int bid = blockIdx.x;
    int t = threadIdx.x;

    if (bid < CVX_BLOCKS) {
        int i = bid * 256 + t;            // 0 .. NN*16-1
        if (i < NN * 16) {
            int n = i >> 4, c = i & 15;
            int q = c >> 2, sub = c & 3;
            float4 a = ((const float4*)x)[i * 2];
            float4 b = ((const float4*)x)[i * 2 + 1];
            bf16x8 v;
            v[0] = f2bf(a.x); v[1] = f2bf(a.y); v[2] = f2bf(a.z); v[3] = f2bf(a.w);
            v[4] = f2bf(b.x); v[5] = f2bf(b.y); v[6] = f2bf(b.z); v[7] = f2bf(b.w);
            *(bf16x8*)(xq + (size_t)q * QS + n * 32 + sub * 8) = v;
        }
        return;
    }
    if (bid < CVX_BLOCKS + CVW_BLOCKS) {
        int i = (bid - CVX_BLOCKS) * 256 + t;
        if (i < 5 * NF * NF) {
            int m = i >> 14, off = i & (NF * NF - 1);
            float v = (m == 0) ? g1[off] : (m == 1) ? g2[off] : (m == 2) ? b1[off]
                    : (m == 3) ? b2[off] : lin[off];
            wbf[i] = f2bf(v);
        }
        return;
    }
    // ---- p0: coarse bucket counting ----
    int pb = bid - CVX_BLOCKS - CVW_BLOCKS;
    for (int i = t; i < 2 * NB; i += 256) cnt[i] = 0;
    __syncthreads();
    int lo = pb * PCHUNK;
    int hi = min(lo + PCHUNK, NE);
    for (int j = lo + t; j < hi; j += 256) {
        int r = ei[j];
        int c = ei[NE + j];
        atomicAdd(&cnt[r >> SHIFT], 1);
        atomicAdd(&cnt[NB + (c >> SHIFT)], 1);
    }
    __syncthreads();
    for (int i = t; i < 2 * NB; i += 256)
        if (cnt[i]) atomicAdd(&gcnt[i], cnt[i]);
}

// ---------------------------------------------------------------------------
// P1: scan bucket counts -> bases + cursors (one block)
// ---------------------------------------------------------------------------
__global__ __launch_bounds__(256) void p1_scan_kernel(const int* __restrict__ gcnt,
                                                      int* __restrict__ baseR,
                                                      int* __restrict__ baseC,
                                                      int* __restrict__ gcur) {
    __shared__ int s[256];
    int t = threadIdx.x;
    int v = (t < NB) ? gcnt[t] : 0;
    s[t] = v;
    __syncthreads();
    for (int off = 1; off < 256; off <<= 1) {
        int u = (t >= off) ? s[t - off] : 0;
        __syncthreads();
        s[t] += u;
        __syncthreads();
    }
    if (t < NB) {
        int excl = s[t] - v;
        baseR[t] = excl;
        gcur[t] = excl;
        if (t == NB - 1) baseR[NB] = s[t];
    }
    __syncthreads();
    int v2 = (t < NB) ? gcnt[NB + t] : 0;
    s[t] = v2;
    __syncthreads();
    for (int off = 1; off < 256; off <<= 1) {
        int u = (t >= off) ? s[t - off] : 0;
        __syncthreads();
        s[t] += u;
        __syncthreads();
    }
    if (t < NB) {
        int excl = s[t] - v2;
        baseC[t] = excl;
        gcur[NB + t] = excl;
        if (t == NB - 1) baseC[NB] = s[t];
    }
}

// ---------------------------------------------------------------------------
// P2: partition edges into bucket-contiguous arrays, 4B packed entries
// ---------------------------------------------------------------------------
__global__ __launch_bounds__(256) void p2_partition_kernel(const int* __restrict__ ei,
                                                           int* __restrict__ gcur,
                                                           unsigned* __restrict__ partR,
                                                           unsigned* __restrict__ partC) {
    __shared__ int cnt[2 * NB];
    __shared__ int res[2 * NB];
    int t = threadIdx.x;
    for (int i = t; i < 2 * NB; i += 256) cnt[i] = 0;
    __syncthreads();
    int lo = blockIdx.x * PCHUNK;
    int hi = min(lo + PCHUNK, NE);
    for (int j = lo + t; j < hi; j += 256) {
        int r = ei[j];
        int c = ei[NE + j];
        atomicAdd(&cnt[r >> SHIFT], 1);
        atomicAdd(&cnt[NB + (c >> SHIFT)], 1);
    }
    __syncthreads();
    for (int i = t; i < 2 * NB; i += 256) {
        int n = cnt[i];
        res[i] = n ? atomicAdd(&gcur[i], n) : 0;
        cnt[i] = 0;
    }
    __syncthreads();
    for (int j = lo + t; j < hi; j += 256) {
        int r = ei[j];
        int c = ei[NE + j];
        int bR = r >> SHIFT;
        int sR = atomicAdd(&cnt[bR], 1);
        partR[res[bR] + sR] = ((unsigned)(r & 255) << 17) | (unsigned)c;
        int bC = NB + (c >> SHIFT);
        int sC = atomicAdd(&cnt[bC], 1);
        partC[res[bC] + sC] = ((unsigned)(c & 255) << 17) | (unsigned)r;
    }
}

// ---------------------------------------------------------------------------
// P3: per (side,bucket): degree count -> scan -> offs/deg/dinv -> place CSR.
// Side-1 blocks additionally emit xdq = dinv * x (quarter-split, bf16).
// ---------------------------------------------------------------------------
__global__ __launch_bounds__(256) void p3_build_kernel(
    const unsigned* __restrict__ partR, const unsigned* __restrict__ partC,
    const int* __restrict__ baseR, const int* __restrict__ baseC,
    int* __restrict__ offs_r, int* __restrict__ offs_c,
    int* __restrict__ csr_r, int* __restrict__ csr_c,
    int* __restrict__ degr, float* __restrict__ dinv,
    const short* __restrict__ xq, short* __restrict__ xdq) {
    int side = blockIdx.x / NB;
    int b = blockIdx.x - side * NB;
    const unsigned* part = side ? partC : partR;
    const int* base = side ? baseC : baseR;
    int* offs = side ? offs_c : offs_r;
    int* csr = side ? csr_c : csr_r;

    __shared__ int deg[256];
    __shared__ int cur[256];
    __shared__ float dinvs[256];
    int t = threadIdx.x;
    int s0 = base[b], s1 = base[b + 1];
    deg[t] = 0;
    __syncthreads();
    for (int j = s0 + t; j < s1; j += 256)
        atomicAdd(&deg[part[j] >> 17], 1);
    __syncthreads();
    int myDeg = deg[t];
    for (int off = 1; off < 256; off <<= 1) {
        int u = (t >= off) ? deg[t - off] : 0;
        __syncthreads();
        deg[t] += u;
        __syncthreads();
    }
    int excl = deg[t] - myDeg;
    int node = (b << SHIFT) + t;
    if (node <= NN) offs[node] = s0 + excl;
    if (node < NN) {
        if (side == 0) degr[node] = myDeg;
        else {
            float dc = rsqrtf((float)myDeg + 1.0f);
            dinv[node] = dc;
            dinvs[t] = dc;
        }
    }
    cur[t] = excl;
    __syncthreads();
    for (int j = s0 + t; j < s1; j += 256) {
        unsigned en = part[j];
        int k = en >> 17;
        int p = atomicAdd(&cur[k], 1);
        csr[s0 + p] = (int)(en & 0x1FFFFu);
    }
    if (side == 1) {
        // xdq = dinv * x for this bucket's 256 nodes; coalesced: 4 lanes/node
        #pragma unroll 1
        for (int pass = 0; pass < 4; ++pass) {
            int nl = pass * 64 + (t >> 2);
            int ci = t & 3;
            int node2 = (b << SHIFT) + nl;
            if (node2 < NN) {
                float dc = dinvs[nl];
                #pragma unroll
                for (int qi = 0; qi < 4; ++qi) {
                    bf16x8 v = *(const bf16x8*)(xq + (size_t)qi * QS + node2 * 32 + ci * 8);
                    bf16x8 o;
                    #pragma unroll
                    for (int k = 0; k < 8; ++k) o[k] = f2bf(dc * bf2f(v[k]));
                    *(bf16x8*)(xdq + (size_t)qi * QS + node2 * 32 + ci * 8) = o;
                }
            }
        }
    }
}

// ---------------------------------------------------------------------------
// K6: gather v6 — side-split XCD pinning (r14) + low-VALU accumulate:
// int4 row loads, bf16 pair-extract (shl/and, 1 op/feat), float2 pk adds.
// ---------------------------------------------------------------------------
__global__ __launch_bounds__(256) void gather_fused_kernel(
    const int* __restrict__ offs_r, const int* __restrict__ csr_r,
    const int* __restrict__ offs_c, const int* __restrict__ csr_c,
    const short* __restrict__ xq, const short* __restrict__ xdq,
    const float* __restrict__ dinv,
    short* __restrict__ nbq, short* __restrict__ zq) {
    int lane8 = blockIdx.x & 7;
    int side = lane8 >> 2;            // 0 = nb (row side), 1 = z (col side)
    int q = lane8 & 3;
    int grp = blockIdx.x >> 3;
    int t = threadIdx.x;
    int g = grp * 16 + (t >> 4);      // node (16/block, 4/wave)
    int slot = (t >> 2) & 3;          // pair-slot
    int fl = t & 3;                   // feature lane (8 bf16 each)

    const short* xb = (side ? xdq : xq) + (size_t)q * QS + fl * 8;
    const int* offs = side ? offs_c : offs_r;
    const int* csr  = side ? csr_c  : csr_r;

    int s = offs[g], e = offs[g + 1];
    int deg = e - s;

    f32x2 a[4] = {{0.f, 0.f}, {0.f, 0.f}, {0.f, 0.f}, {0.f, 0.f}};

    // alignment prologue: make start even (node-uniform branch)
    if (s & 1) {
        if (slot == 0) acc8(*(const int4*)(xb + csr[s] * 32), a);
        ++s;
    }
    int npairs = (e - s) >> 1;
    int p = slot;
    for (; p + 4 < npairs; p += 8) {          // 2 int2 in flight per slot
        int2 c0 = *(const int2*)(csr + s + 2 * p);
        int2 c1 = *(const int2*)(csr + s + 2 * p + 8);
        int4 v0 = *(const int4*)(xb + c0.x * 32);
        int4 v1 = *(const int4*)(xb + c0.y * 32);
        int4 v2 = *(const int4*)(xb + c1.x * 32);
        int4 v3 = *(const int4*)(xb + c1.y * 32);
        acc8(v0, a); acc8(v1, a); acc8(v2, a); acc8(v3, a);
    }
    for (; p < npairs; p += 4) {
        int2 c0 = *(const int2*)(csr + s + 2 * p);
        int4 v0 = *(const int4*)(xb + c0.x * 32);
        int4 v1 = *(const int4*)(xb + c0.y * 32);
        acc8(v0, a); acc8(v1, a);
    }
    if (((e - s) & 1) && slot == 0)           // odd tail edge
        acc8(*(const int4*)(xb + csr[e - 1] * 32), a);

    // merge the 4 pair-slots (xor 4, 8 stay within the node's 16 lanes)
    #pragma unroll
    for (int i = 0; i < 4; ++i) {
        a[i].x += __shfl_xor(a[i].x, 4);
        a[i].y += __shfl_xor(a[i].y, 4);
        a[i].x += __shfl_xor(a[i].x, 8);
        a[i].y += __shfl_xor(a[i].y, 8);
    }

    if (slot == 0) {
        if (side == 0) {
            float invn = 1.0f / fmaxf((float)deg, 1.0f);
            bf16x8 o;
            #pragma unroll
            for (int i = 0; i < 4; ++i) {
                o[2 * i]     = f2bf(a[i].x * invn);
                o[2 * i + 1] = f2bf(a[i].y * invn);
            }
            *(bf16x8*)(nbq + (size_t)q * QS + g * 32 + fl * 8) = o;
        } else {
            float dc = dinv[g];
            bf16x8 self = *(const bf16x8*)(xb + g * 32);   // xdq self row
            bf16x8 zo;
            #pragma unroll
            for (int i = 0; i < 4; ++i) {
                zo[2 * i]     = f2bf(dc * (a[i].x + bf2f(self[2 * i])));
                zo[2 * i + 1] = f2bf(dc * (a[i].y + bf2f(self[2 * i + 1])));
            }
            *(bf16x8*)(zq + (size_t)q * QS + g * 32 + fl * 8) = zo;
        }
    }
}

// ---------------------------------------------------------------------------
// K7: fused FiLM (4 GEMMs) + final GEMM, MFMA 16x16x32 bf16.
// Register-resident weights; stages from quarter-split arrays.
// FBLOCKS = NTILES: exactly one 64-node tile per block (no straggler round).
// ---------------------------------------------------------------------------
__global__ __launch_bounds__(256, 2) void film_mfma_kernel(
    const short* __restrict__ xq, const short* __restrict__ nbq,
    const short* __restrict__ zq, const short* __restrict__ wbf,
    const float* __restrict__ rvec, const float* __restrict__ bias,
    const int* __restrict__ degr, float* __restrict__ outp,
    float* __restrict__ hko) {
    __shared__ short xs[64 * NF];
    __shared__ short ns[64 * NF];
    __shared__ short zs[64 * NF];

    int tid = threadIdx.x;
    int w = tid >> 6;
    int l = tid & 63;
    int lr = l & 15;
    int lg = l >> 4;

    bf16x8 wf[2][5][4];
    float rc[2], bc[2];
    #pragma unroll
    for (int j = 0; j < 2; ++j) {
        int col = (2 * w + j) * 16 + lr;
        #pragma unroll
        for (int m = 0; m < 5; ++m) {
            const short* wm = wbf + m * 16384 + col * NF;
            #pragma unroll
            for (int kb = 0; kb < 4; ++kb)
                wf[j][m][kb] = *(const bf16x8*)(wm + kb * 32 + lg * 8);
        }
        rc[j] = rvec[col];
        bc[j] = bias[col];
    }

    int tile = blockIdx.x;
    {
        int node0 = tile * 64;

        #pragma unroll
        for (int it = 0; it < 4; ++it) {
            int chunk = it * 256 + tid;          // 0..1023
            int row = chunk >> 4;
            int c = chunk & 15;
            int grow = min(node0 + row, NN - 1);
            int swz = ((c ^ (row & 7)) << 3);
            size_t qoff = (size_t)(c >> 2) * QS + grow * 32 + (c & 3) * 8;
            *(bf16x8*)(xs + row * NF + swz) = *(const bf16x8*)(xq + qoff);
            *(bf16x8*)(ns + row * NF + swz) = *(const bf16x8*)(nbq + qoff);
            *(bf16x8*)(zs + row * NF + swz) = *(const bf16x8*)(zq + qoff);
        }
        __syncthreads();

        #pragma unroll 1
        for (int rg = 0; rg < 4; ++rg) {
            bf16x8 xf[4], nf[4];
            #pragma unroll
            for (int kb = 0; kb < 4; ++kb) {
                int row = rg * 16 + lr;
                int swz = (((kb * 4 + lg) ^ (row & 7)) << 3);
                xf[kb] = *(const bf16x8*)(xs + row * NF + swz);
                nf[kb] = *(const bf16x8*)(ns + row * NF + swz);
            }
            #pragma unroll
            for (int j = 0; j < 2; ++j) {
                f32x4 ag = {0.f, 0.f, 0.f, 0.f};
                f32x4 ab = {0.f, 0.f, 0.f, 0.f};
                #pragma unroll
                for (int kb = 0; kb < 4; ++kb) {
                    ag = __builtin_amdgcn_mfma_f32_16x16x32_bf16(xf[kb], wf[j][0][kb], ag, 0, 0, 0);
                    ag = __builtin_amdgcn_mfma_f32_16x16x32_bf16(nf[kb], wf[j][1][kb], ag, 0, 0, 0);
                    ab = __builtin_amdgcn_mfma_f32_16x16x32_bf16(xf[kb], wf[j][2][kb], ab, 0, 0, 0);
                    ab = __builtin_amdgcn_mfma_f32_16x16x32_bf16(nf[kb], wf[j][3][kb], ab, 0, 0, 0);
                }
                int col = (2 * w + j) * 16 + lr;
                #pragma unroll
                for (int q = 0; q < 4; ++q) {
                    int nl = rg * 16 + lg * 4 + q;
                    int ng = node0 + nl;
                    int addr = nl * NF + (((col >> 3) ^ (nl & 7)) << 3) + (col & 7);
                    float xv = bf2f(xs[addr]);
                    float nv = bf2f(ns[addr]);
                    float gp = ag[q], bp = ab[q];
                    float gamma = (gp >= 0.f ? gp : 0.2f * gp) + 1.0f;
                    float beta  = (bp >= 0.f ? bp : 0.2f * bp);
                    float o = xv + gamma * rc[j] + beta - nv;
                    if (ng < NN) outp[ng * NF + col] = o;
                    zs[addr] = f2bf(o + bf2f(zs[addr]));   // t = output + z, in place
                }
            }
        }
        __syncthreads();

        #pragma unroll 1
        for (int rg = 0; rg < 4; ++rg) {
            bf16x8 of[4];
            #pragma unroll
            for (int kb = 0; kb < 4; ++kb) {
                int row = rg * 16 + lr;
                int swz = (((kb * 4 + lg) ^ (row & 7)) << 3);
                of[kb] = *(const bf16x8*)(zs + row * NF + swz);
            }
            float invdq[4];
            #pragma unroll
            for (int q = 0; q < 4; ++q)
                invdq[q] = 1.0f / ((float)degr[min(node0 + rg * 16 + lg * 4 + q, NN - 1)] + 1.0f);
            #pragma unroll
            for (int j = 0; j < 2; ++j) {
                f32x4 as = {0.f, 0.f, 0.f, 0.f};
                #pragma unroll
                for (int kb = 0; kb < 4; ++kb)
                    as = __builtin_amdgcn_mfma_f32_16x16x32_bf16(of[kb], wf[j][4][kb], as, 0, 0, 0);
                int col = (2 * w + j) * 16 + lr;
                #pragma unroll
                for (int q = 0; q < 4; ++q) {
                    int ng = node0 + rg * 16 + lg * 4 + q;
                    if (ng < NN) hko[ng * NF + col] = (as[q] + bc[j]) * invdq[q];
                }
            }
        }
    }
}

// ---------------------------------------------------------------------------
extern "C" void kernel_launch(void* const* d_in, const int* in_sizes, int n_in,
                              void* d_out, int out_size, void* d_ws, size_t ws_size,
                              hipStream_t stream) {
    const float* x    = (const float*)d_in[0];
    const int*   ei   = (const int*)d_in[1];
    const float* g1   = (const float*)d_in[3];
    const float* g2   = (const float*)d_in[4];
    const float* b1   = (const float*)d_in[5];
    const float* b2   = (const float*)d_in[6];
    const float* rv   = (const float*)d_in[7];
    const float* lin  = (const float*)d_in[8];
    const float* bias = (const float*)d_in[9];

    float* dinv = (float*)d_ws;                  // N
    int* degr   = (int*)(dinv + NN);             // N
    int* offs_r = degr + NN;                     // N+2 (padded even)
    int* offs_c = offs_r + (NN + 2);             // N+2
    int* csr_r  = offs_c + (NN + 2);             // E  (8B-aligned)
    int* csr_c  = csr_r + NE;                    // E
    unsigned* partR = (unsigned*)(csr_c + NE);   // E
    unsigned* partC = partR + NE;                // E
    int* gcnt   = (int*)(partC + NE);            // 2*NB (zeroed)
    int* gcur   = gcnt + 2 * NB;                 // 2*NB
    int* baseR  = gcur + 2 * NB;                 // NB+1
    int* baseC  = baseR + (NB + 1);              // NB+1
    uintptr_t p = (uintptr_t)(baseC + NB + 1);
    p = (p + 15) & ~(uintptr_t)15;
    short* xq   = (short*)p;                     // 4*QS bf16 (quarter-split x)
    short* nbq  = xq + 4 * QS;                   // 4*QS bf16
    short* zq   = nbq + 4 * QS;                  // 4*QS bf16
    short* xdq  = zq + 4 * QS;                   // 4*QS bf16 (dinv-folded x)
    short* wbf  = xdq + 4 * QS;                  // 5*128*128 bf16

    float* hko  = (float*)d_out;                 // N*F (h_k)
    float* outp = hko + NN * NF;                 // N*F (output)

    hipMemsetAsync(gcnt, 0, 2 * NB * sizeof(int), stream);

    prep_kernel<<<PREP_BLOCKS, 256, 0, stream>>>(x, g1, g2, b1, b2, lin, ei,
                                                 xq, wbf, gcnt);
    p1_scan_kernel<<<1, 256, 0, stream>>>(gcnt, baseR, baseC, gcur);
    p2_partition_kernel<<<PBLOCKS, 256, 0, stream>>>(ei, gcur, partR, partC);
    p3_build_kernel<<<2 * NB, 256, 0, stream>>>(partR, partC, baseR, baseC,
                                                offs_r, offs_c, csr_r, csr_c,
                                                degr, dinv, xq, xdq);
    gather_fused_kernel<<<((NN + 15) / 16) * 8, 256, 0, stream>>>(
        offs_r, csr_r, offs_c, csr_c, xq, xdq, dinv, nbq, zq);
    film_mfma_kernel<<<FBLOCKS, 256, 0, stream>>>(xq, nbq, zq, wbf, rv, bias, degr,
                                                  outp, hko);
}

// Round 16
// 160.896 us; speedup vs baseline: 1.0481x; 1.0481x over previous
//
#include <hip/hip_runtime.h>

#define NN 50000
#define NE 800000
#define NF 128
#define QS (NN * 32)      // quarter stride (shorts): [q][node][32]

#define SHIFT 8
#define NB 196            // ceil(50000/256)
#define PBLOCKS 128
#define PCHUNK ((NE + PBLOCKS - 1) / PBLOCKS)   // 6250

#define NTILES ((NN + 63) / 64)   // 782
#define FBLOCKS 391               // exactly 2 tiles per block, uniform

// prep kernel block ranges
#define CVX_BLOCKS 3125   // convert_x: 50000*16 chunks / 256
#define CVW_BLOCKS 320    // convert_w: 5*16384/256
#define PREP_BLOCKS (CVX_BLOCKS + CVW_BLOCKS + PBLOCKS)

typedef __attribute__((ext_vector_type(4))) float f32x4;
typedef __attribute__((ext_vector_type(8))) short bf16x8;

__device__ __forceinline__ short f2bf(float f) {
    unsigned u = __float_as_uint(f);
    u += 0x7FFF + ((u >> 16) & 1);      // round-to-nearest-even
    return (short)(u >> 16);
}
__device__ __forceinline__ float bf2f(short s) {
    return __uint_as_float(((unsigned)(unsigned short)s) << 16);
}

// ---------------------------------------------------------------------------
// PREP: fused convert_x (quarter-split) + convert_w + p0 bucket counting
// ---------------------------------------------------------------------------
__global__ __launch_bounds__(256) void prep_kernel(
    const float* __restrict__ x, const float* __restrict__ g1,
    const float* __restrict__ g2, const float* __restrict__ b1,
    const float* __restrict__ b2, const float* __restrict__ lin,
    const int* __restrict__ ei, short* __restrict__ xq,
    short* __restrict__ wbf, int* __restrict__ gcnt) {
    __shared__ int cnt[2 * NB];
    int bid = blockIdx.x;
    int t = threadIdx.x;

    if (bid < CVX_BLOCKS) {
        int i = bid * 256 + t;            // 0 .. NN*16-1
        if (i < NN * 16) {
            int n = i >> 4, c = i & 15;
            int q = c >> 2, sub = c & 3;
            float4 a = ((const float4*)x)[i * 2];
            float4 b = ((const float4*)x)[i * 2 + 1];
            bf16x8 v;
            v[0] = f2bf(a.x); v[1] = f2bf(a.y); v[2] = f2bf(a.z); v[3] = f2bf(a.w);
            v[4] = f2bf(b.x); v[5] = f2bf(b.y); v[6] = f2bf(b.z); v[7] = f2bf(b.w);
            *(bf16x8*)(xq + (size_t)q * QS + n * 32 + sub * 8) = v;
        }
        return;
    }
    if (bid < CVX_BLOCKS + CVW_BLOCKS) {
        int i = (bid - CVX_BLOCKS) * 256 + t;
        if (i < 5 * NF * NF) {
            int m = i >> 14, off = i & (NF * NF - 1);
            float v = (m == 0) ? g1[off] : (m == 1) ? g2[off] : (m == 2) ? b1[off]
                    : (m == 3) ? b2[off] : lin[off];
            wbf[i] = f2bf(v);
        }
        return;
    }
    // ---- p0: coarse bucket counting ----
    int pb = bid - CVX_BLOCKS - CVW_BLOCKS;
    for (int i = t; i < 2 * NB; i += 256) cnt[i] = 0;
    __syncthreads();
    int lo = pb * PCHUNK;
    int hi = min(lo + PCHUNK, NE);
    for (int j = lo + t; j < hi; j += 256) {
        int r = ei[j];
        int c = ei[NE + j];
        atomicAdd(&cnt[r >> SHIFT], 1);
        atomicAdd(&cnt[NB + (c >> SHIFT)], 1);
    }
    __syncthreads();
    for (int i = t; i < 2 * NB; i += 256)
        if (cnt[i]) atomicAdd(&gcnt[i], cnt[i]);
}

// ---------------------------------------------------------------------------
// P1: scan bucket counts -> bases + cursors (one block)
// ---------------------------------------------------------------------------
__global__ __launch_bounds__(256) void p1_scan_kernel(const int* __restrict__ gcnt,
                                                      int* __restrict__ baseR,
                                                      int* __restrict__ baseC,
                                                      int* __restrict__ gcur) {
    __shared__ int s[256];
    int t = threadIdx.x;
    int v = (t < NB) ? gcnt[t] : 0;
    s[t] = v;
    __syncthreads();
    for (int off = 1; off < 256; off <<= 1) {
        int u = (t >= off) ? s[t - off] : 0;
        __syncthreads();
        s[t] += u;
        __syncthreads();
    }
    if (t < NB) {
        int excl = s[t] - v;
        baseR[t] = excl;
        gcur[t] = excl;
        if (t == NB - 1) baseR[NB] = s[t];
    }
    __syncthreads();
    int v2 = (t < NB) ? gcnt[NB + t] : 0;
    s[t] = v2;
    __syncthreads();
    for (int off = 1; off < 256; off <<= 1) {
        int u = (t >= off) ? s[t - off] : 0;
        __syncthreads();
        s[t] += u;
        __syncthreads();
    }
    if (t < NB) {
        int excl = s[t] - v2;
        baseC[t] = excl;
        gcur[NB + t] = excl;
        if (t == NB - 1) baseC[NB] = s[t];
    }
}

// ---------------------------------------------------------------------------
// P2: partition edges into bucket-contiguous arrays, 4B packed entries
// ---------------------------------------------------------------------------
__global__ __launch_bounds__(256) void p2_partition_kernel(const int* __restrict__ ei,
                                                           int* __restrict__ gcur,
                                                           unsigned* __restrict__ partR,
                                                           unsigned* __restrict__ partC) {
    __shared__ int cnt[2 * NB];
    __shared__ int res[2 * NB];
    int t = threadIdx.x;
    for (int i = t; i < 2 * NB; i += 256) cnt[i] = 0;
    __syncthreads();
    int lo = blockIdx.x * PCHUNK;
    int hi = min(lo + PCHUNK, NE);
    for (int j = lo + t; j < hi; j += 256) {
        int r = ei[j];
        int c = ei[NE + j];
        atomicAdd(&cnt[r >> SHIFT], 1);
        atomicAdd(&cnt[NB + (c >> SHIFT)], 1);
    }
    __syncthreads();
    for (int i = t; i < 2 * NB; i += 256) {
        int n = cnt[i];
        res[i] = n ? atomicAdd(&gcur[i], n) : 0;
        cnt[i] = 0;
    }
    __syncthreads();
    for (int j = lo + t; j < hi; j += 256) {
        int r = ei[j];
        int c = ei[NE + j];
        int bR = r >> SHIFT;
        int sR = atomicAdd(&cnt[bR], 1);
        partR[res[bR] + sR] = ((unsigned)(r & 255) << 17) | (unsigned)c;
        int bC = NB + (c >> SHIFT);
        int sC = atomicAdd(&cnt[bC], 1);
        partC[res[bC] + sC] = ((unsigned)(c & 255) << 17) | (unsigned)r;
    }
}

// ---------------------------------------------------------------------------
// P3: per (side,bucket): degree count -> scan -> offs/deg/dinv -> place CSR.
// Side-1 blocks additionally emit xdq = dinv * x (quarter-split, bf16).
// ---------------------------------------------------------------------------
__global__ __launch_bounds__(256) void p3_build_kernel(
    const unsigned* __restrict__ partR, const unsigned* __restrict__ partC,
    const int* __restrict__ baseR, const int* __restrict__ baseC,
    int* __restrict__ offs_r, int* __restrict__ offs_c,
    int* __restrict__ csr_r, int* __restrict__ csr_c,
    int* __restrict__ degr, float* __restrict__ dinv,
    const short* __restrict__ xq, short* __restrict__ xdq) {
    int side = blockIdx.x / NB;
    int b = blockIdx.x - side * NB;
    const unsigned* part = side ? partC : partR;
    const int* base = side ? baseC : baseR;
    int* offs = side ? offs_c : offs_r;
    int* csr = side ? csr_c : csr_r;

    __shared__ int deg[256];
    __shared__ int cur[256];
    __shared__ float dinvs[256];
    int t = threadIdx.x;
    int s0 = base[b], s1 = base[b + 1];
    deg[t] = 0;
    __syncthreads();
    for (int j = s0 + t; j < s1; j += 256)
        atomicAdd(&deg[part[j] >> 17], 1);
    __syncthreads();
    int myDeg = deg[t];
    for (int off = 1; off < 256; off <<= 1) {
        int u = (t >= off) ? deg[t - off] : 0;
        __syncthreads();
        deg[t] += u;
        __syncthreads();
    }
    int excl = deg[t] - myDeg;
    int node = (b << SHIFT) + t;
    if (node <= NN) offs[node] = s0 + excl;
    if (node < NN) {
        if (side == 0) degr[node] = myDeg;
        else {
            float dc = rsqrtf((float)myDeg + 1.0f);
            dinv[node] = dc;
            dinvs[t] = dc;
        }
    }
    cur[t] = excl;
    __syncthreads();
    for (int j = s0 + t; j < s1; j += 256) {
        unsigned en = part[j];
        int k = en >> 17;
        int p = atomicAdd(&cur[k], 1);
        csr[s0 + p] = (int)(en & 0x1FFFFu);
    }
    if (side == 1) {
        // xdq = dinv * x for this bucket's 256 nodes; coalesced: 4 lanes/node
        #pragma unroll 1
        for (int pass = 0; pass < 4; ++pass) {
            int nl = pass * 64 + (t >> 2);
            int ci = t & 3;
            int node2 = (b << SHIFT) + nl;
            if (node2 < NN) {
                float dc = dinvs[nl];
                #pragma unroll
                for (int qi = 0; qi < 4; ++qi) {
                    bf16x8 v = *(const bf16x8*)(xq + (size_t)qi * QS + node2 * 32 + ci * 8);
                    bf16x8 o;
                    #pragma unroll
                    for (int k = 0; k < 8; ++k) o[k] = f2bf(dc * bf2f(v[k]));
                    *(bf16x8*)(xdq + (size_t)qi * QS + node2 * 32 + ci * 8) = o;
                }
            }
        }
    }
}

// ---------------------------------------------------------------------------
// K6: gather v5 (r14 best) — SIDE-SPLIT XCD pinning. blockIdx&7: 0-3 =
// nb-gather over xq[quarter], 4-7 = z-gather over xdq[quarter]. Each XCD
// touches ONE 3.2 MB array quarter (L2-resident), both sides plain sums.
// 16 lanes/node (4 pair-slots x 4 flanes), int2 CSR, trip = deg/8.
// ---------------------------------------------------------------------------
__global__ __launch_bounds__(256) void gather_fused_kernel(
    const int* __restrict__ offs_r, const int* __restrict__ csr_r,
    const int* __restrict__ offs_c, const int* __restrict__ csr_c,
    const short* __restrict__ xq, const short* __restrict__ xdq,
    const float* __restrict__ dinv,
    short* __restrict__ nbq, short* __restrict__ zq) {
    int lane8 = blockIdx.x & 7;
    int side = lane8 >> 2;            // 0 = nb (row side), 1 = z (col side)
    int q = lane8 & 3;
    int grp = blockIdx.x >> 3;
    int t = threadIdx.x;
    int g = grp * 16 + (t >> 4);      // node (16/block, 4/wave)
    int slot = (t >> 2) & 3;          // pair-slot
    int fl = t & 3;                   // feature lane (8 bf16 each)

    const short* xb = (side ? xdq : xq) + (size_t)q * QS + fl * 8;
    const int* offs = side ? offs_c : offs_r;
    const int* csr  = side ? csr_c  : csr_r;

    int s = offs[g], e = offs[g + 1];
    int deg = e - s;

    float acc[8] = {0.f, 0.f, 0.f, 0.f, 0.f, 0.f, 0.f, 0.f};

    // alignment prologue: make start even (node-uniform branch)
    if (s & 1) {
        if (slot == 0) {
            bf16x8 v = *(const bf16x8*)(xb + csr[s] * 32);
            #pragma unroll
            for (int k = 0; k < 8; ++k) acc[k] += bf2f(v[k]);
        }
        ++s;
    }
    int npairs = (e - s) >> 1;
    int p = slot;
    for (; p + 4 < npairs; p += 8) {          // 2 int2 in flight per slot
        int2 c0 = *(const int2*)(csr + s + 2 * p);
        int2 c1 = *(const int2*)(csr + s + 2 * p + 8);
        bf16x8 v0 = *(const bf16x8*)(xb + c0.x * 32);
        bf16x8 v1 = *(const bf16x8*)(xb + c0.y * 32);
        bf16x8 v2 = *(const bf16x8*)(xb + c1.x * 32);
        bf16x8 v3 = *(const bf16x8*)(xb + c1.y * 32);
        #pragma unroll
        for (int k = 0; k < 8; ++k)
            acc[k] += (bf2f(v0[k]) + bf2f(v1[k])) + (bf2f(v2[k]) + bf2f(v3[k]));
    }
    for (; p < npairs; p += 4) {
        int2 c0 = *(const int2*)(csr + s + 2 * p);
        bf16x8 v0 = *(const bf16x8*)(xb + c0.x * 32);
        bf16x8 v1 = *(const bf16x8*)(xb + c0.y * 32);
        #pragma unroll
        for (int k = 0; k < 8; ++k) acc[k] += bf2f(v0[k]) + bf2f(v1[k]);
    }
    if (((e - s) & 1) && slot == 0) {         // odd tail edge
        bf16x8 v = *(const bf16x8*)(xb + csr[e - 1] * 32);
        #pragma unroll
        for (int k = 0; k < 8; ++k) acc[k] += bf2f(v[k]);
    }

    // merge the 4 pair-slots (xor 4, 8 stay within the node's 16 lanes)
    #pragma unroll
    for (int k = 0; k < 8; ++k) {
        acc[k] += __shfl_xor(acc[k], 4);
        acc[k] += __shfl_xor(acc[k], 8);
    }

    if (slot == 0) {
        if (side == 0) {
            float invn = 1.0f / fmaxf((float)deg, 1.0f);
            bf16x8 o;
            #pragma unroll
            for (int k = 0; k < 8; ++k) o[k] = f2bf(acc[k] * invn);
            *(bf16x8*)(nbq + (size_t)q * QS + g * 32 + fl * 8) = o;
        } else {
            float dc = dinv[g];
            bf16x8 self = *(const bf16x8*)(xb + g * 32);   // xdq self row
            bf16x8 zo;
            #pragma unroll
            for (int k = 0; k < 8; ++k) zo[k] = f2bf(dc * (acc[k] + bf2f(self[k])));
            *(bf16x8*)(zq + (size_t)q * QS + g * 32 + fl * 8) = zo;
        }
    }
}

// ---------------------------------------------------------------------------
// K7: fused FiLM (4 GEMMs) + final GEMM, MFMA 16x16x32 bf16.
// Register-resident weights; stages from quarter-split arrays.
// FBLOCKS = 391: exactly 2 tiles per block (782 = 391*2) -> uniform work,
// weight refetch 391*160KB = 62 MB (vs 125 MB at 782 blocks).
// ---------------------------------------------------------------------------
__global__ __launch_bounds__(256, 2) void film_mfma_kernel(
    const short* __restrict__ xq, const short* __restrict__ nbq,
    const short* __restrict__ zq, const short* __restrict__ wbf,
    const float* __restrict__ rvec, const float* __restrict__ bias,
    const int* __restrict__ degr, float* __restrict__ outp,
    float* __restrict__ hko) {
    __shared__ short xs[64 * NF];
    __shared__ short ns[64 * NF];
    __shared__ short zs[64 * NF];

    int tid = threadIdx.x;
    int w = tid >> 6;
    int l = tid & 63;
    int lr = l & 15;
    int lg = l >> 4;

    bf16x8 wf[2][5][4];
    float rc[2], bc[2];
    #pragma unroll
    for (int j = 0; j < 2; ++j) {
        int col = (2 * w + j) * 16 + lr;
        #pragma unroll
        for (int m = 0; m < 5; ++m) {
            const short* wm = wbf + m * 16384 + col * NF;
            #pragma unroll
            for (int kb = 0; kb < 4; ++kb)
                wf[j][m][kb] = *(const bf16x8*)(wm + kb * 32 + lg * 8);
        }
        rc[j] = rvec[col];
        bc[j] = bias[col];
    }

    #pragma unroll 1
    for (int tile = blockIdx.x; tile < NTILES; tile += FBLOCKS) {
        int node0 = tile * 64;

        #pragma unroll
        for (int it = 0; it < 4; ++it) {
            int chunk = it * 256 + tid;          // 0..1023
            int row = chunk >> 4;
            int c = chunk & 15;
            int grow = min(node0 + row, NN - 1);
            int swz = ((c ^ (row & 7)) << 3);
            size_t qoff = (size_t)(c >> 2) * QS + grow * 32 + (c & 3) * 8;
            *(bf16x8*)(xs + row * NF + swz) = *(const bf16x8*)(xq + qoff);
            *(bf16x8*)(ns + row * NF + swz) = *(const bf16x8*)(nbq + qoff);
            *(bf16x8*)(zs + row * NF + swz) = *(const bf16x8*)(zq + qoff);
        }
        __syncthreads();

        #pragma unroll 1
        for (int rg = 0; rg < 4; ++rg) {
            bf16x8 xf[4], nf[4];
            #pragma unroll
            for (int kb = 0; kb < 4; ++kb) {
                int row = rg * 16 + lr;
                int swz = (((kb * 4 + lg) ^ (row & 7)) << 3);
                xf[kb] = *(const bf16x8*)(xs + row * NF + swz);
                nf[kb] = *(const bf16x8*)(ns + row * NF + swz);
            }
            #pragma unroll
            for (int j = 0; j < 2; ++j) {
                f32x4 ag = {0.f, 0.f, 0.f, 0.f};
                f32x4 ab = {0.f, 0.f, 0.f, 0.f};
                #pragma unroll
                for (int kb = 0; kb < 4; ++kb) {
                    ag = __builtin_amdgcn_mfma_f32_16x16x32_bf16(xf[kb], wf[j][0][kb], ag, 0, 0, 0);
                    ag = __builtin_amdgcn_mfma_f32_16x16x32_bf16(nf[kb], wf[j][1][kb], ag, 0, 0, 0);
                    ab = __builtin_amdgcn_mfma_f32_16x16x32_bf16(xf[kb], wf[j][2][kb], ab, 0, 0, 0);
                    ab = __builtin_amdgcn_mfma_f32_16x16x32_bf16(nf[kb], wf[j][3][kb], ab, 0, 0, 0);
                }
                int col = (2 * w + j) * 16 + lr;
                #pragma unroll
                for (int q = 0; q < 4; ++q) {
                    int nl = rg * 16 + lg * 4 + q;
                    int ng = node0 + nl;
                    int addr = nl * NF + (((col >> 3) ^ (nl & 7)) << 3) + (col & 7);
                    float xv = bf2f(xs[addr]);
                    float nv = bf2f(ns[addr]);
                    float gp = ag[q], bp = ab[q];
                    float gamma = (gp >= 0.f ? gp : 0.2f * gp) + 1.0f;
                    float beta  = (bp >= 0.f ? bp : 0.2f * bp);
                    float o = xv + gamma * rc[j] + beta - nv;
                    if (ng < NN) outp[ng * NF + col] = o;
                    zs[addr] = f2bf(o + bf2f(zs[addr]));   // t = output + z, in place
                }
            }
        }
        __syncthreads();

        #pragma unroll 1
        for (int rg = 0; rg < 4; ++rg) {
            bf16x8 of[4];
            #pragma unroll
            for (int kb = 0; kb < 4; ++kb) {
                int row = rg * 16 + lr;
                int swz = (((kb * 4 + lg) ^ (row & 7)) << 3);
                of[kb] = *(const bf16x8*)(zs + row * NF + swz);
            }
            float invdq[4];
            #pragma unroll
            for (int q = 0; q < 4; ++q)
                invdq[q] = 1.0f / ((float)degr[min(node0 + rg * 16 + lg * 4 + q, NN - 1)] + 1.0f);
            #pragma unroll
            for (int j = 0; j < 2; ++j) {
                f32x4 as = {0.f, 0.f, 0.f, 0.f};
                #pragma unroll
                for (int kb = 0; kb < 4; ++kb)
                    as = __builtin_amdgcn_mfma_f32_16x16x32_bf16(of[kb], wf[j][4][kb], as, 0, 0, 0);
                int col = (2 * w + j) * 16 + lr;
                #pragma unroll
                for (int q = 0; q < 4; ++q) {
                    int ng = node0 + rg * 16 + lg * 4 + q;
                    if (ng < NN) hko[ng * NF + col] = (as[q] + bc[j]) * invdq[q];
                }
            }
        }
        __syncthreads();
    }
}

// ---------------------------------------------------------------------------
extern "C" void kernel_launch(void* const* d_in, const int* in_sizes, int n_in,
                              void* d_out, int out_size, void* d_ws, size_t ws_size,
                              hipStream_t stream) {
    const float* x    = (const float*)d_in[0];
    const int*   ei   = (const int*)d_in[1];
    const float* g1   = (const float*)d_in[3];
    const float* g2   = (const float*)d_in[4];
    const float* b1   = (const float*)d_in[5];
    const float* b2   = (const float*)d_in[6];
    const float* rv   = (const float*)d_in[7];
    const float* lin  = (const float*)d_in[8];
    const float* bias = (const float*)d_in[9];

    float* dinv = (float*)d_ws;                  // N
    int* degr   = (int*)(dinv + NN);             // N
    int* offs_r = degr + NN;                     // N+2 (padded even)
    int* offs_c = offs_r + (NN + 2);             // N+2
    int* csr_r  = offs_c + (NN + 2);             // E  (8B-aligned)
    int* csr_c  = csr_r + NE;                    // E
    unsigned* partR = (unsigned*)(csr_c + NE);   // E
    unsigned* partC = partR + NE;                // E
    int* gcnt   = (int*)(partC + NE);            // 2*NB (zeroed)
    int* gcur   = gcnt + 2 * NB;                 // 2*NB
    int* baseR  = gcur + 2 * NB;                 // NB+1
    int* baseC  = baseR + (NB + 1);              // NB+1
    uintptr_t p = (uintptr_t)(baseC + NB + 1);
    p = (p + 15) & ~(uintptr_t)15;
    short* xq   = (short*)p;                     // 4*QS bf16 (quarter-split x)
    short* nbq  = xq + 4 * QS;                   // 4*QS bf16
    short* zq   = nbq + 4 * QS;                  // 4*QS bf16
    short* xdq  = zq + 4 * QS;                   // 4*QS bf16 (dinv-folded x)
    short* wbf  = xdq + 4 * QS;                  // 5*128*128 bf16

    float* hko  = (float*)d_out;                 // N*F (h_k)
    float* outp = hko + NN * NF;                 // N*F (output)

    hipMemsetAsync(gcnt, 0, 2 * NB * sizeof(int), stream);

    prep_kernel<<<PREP_BLOCKS, 256, 0, stream>>>(x, g1, g2, b1, b2, lin, ei,
                                                 xq, wbf, gcnt);
    p1_scan_kernel<<<1, 256, 0, stream>>>(gcnt, baseR, baseC, gcur);
    p2_partition_kernel<<<PBLOCKS, 256, 0, stream>>>(ei, gcur, partR, partC);
    p3_build_kernel<<<2 * NB, 256, 0, stream>>>(partR, partC, baseR, baseC,
                                                offs_r, offs_c, csr_r, csr_c,
                                                degr, dinv, xq, xdq);
    gather_fused_kernel<<<((NN + 15) / 16) * 8, 256, 0, stream>>>(
        offs_r, csr_r, offs_c, csr_c, xq, xdq, dinv, nbq, zq);
    film_mfma_kernel<<<FBLOCKS, 256, 0, stream>>>(xq, nbq, zq, wbf, rv, bias, degr,
                                                  outp, hko);
}